// Round 1
// baseline (1303.312 us; speedup 1.0000x reference)
//
#include <hip/hip_runtime.h>
#include <cmath>

// Problem constants (Qwen3 MoE block)
constexpr int T = 2048;   // tokens (B*S)
constexpr int H = 1024;   // hidden
constexpr int I = 768;    // intermediate
constexpr int E = 16;     // experts

// GEMM tiling
constexpr int TM = 32;    // token rows per block
constexpr int TN = 64;    // output cols per block
constexpr int KC = 32;    // K-chunk
constexpr int XPAD = TM + 4;  // 36: keeps float4 reads 16B-aligned, <=4-way store conflict
constexpr int WPAD = TN + 2;  // 66: keeps float2 reads 8B-aligned, 2-way conflicts only

// ------------------------------------------------------------------
// Router: one wave per token. 16 logits -> top2 -> renormalized probs.
// Renormalized top-2 softmax == softmax over the two winning logits
// (the full-Z division cancels), so w1 = 1/(1+exp(l2-l1)).
// ------------------------------------------------------------------
__global__ __launch_bounds__(256) void router_kernel(
    const float* __restrict__ x,     // [T,H]
    const float* __restrict__ gw,    // [E,H]
    int* __restrict__ cnt,           // [E]
    int* __restrict__ entries,       // [E,T]  value = t*2 + k
    float* __restrict__ wlist)       // [E,T]
{
    const int wave = threadIdx.x >> 6;
    const int lane = threadIdx.x & 63;
    const int t = blockIdx.x * 4 + wave;
    const int e = lane >> 2;         // 4 lanes per expert
    const int part = lane & 3;

    const float4* xr = (const float4*)(x + (size_t)t * H);
    const float4* gr = (const float4*)(gw + (size_t)e * H);
    float s = 0.f;
    #pragma unroll 8
    for (int q = 0; q < 64; ++q) {
        float4 a = xr[part * 64 + q];
        float4 b = gr[part * 64 + q];
        s += a.x * b.x + a.y * b.y + a.z * b.z + a.w * b.w;
    }
    s += __shfl_xor(s, 1);
    s += __shfl_xor(s, 2);           // all 4 lanes of group e hold logit_e

    float lg[E];
    #pragma unroll
    for (int k = 0; k < E; ++k) lg[k] = __shfl(s, k * 4);

    // top-1 (first occurrence on ties, matches lax.top_k)
    int i1 = 0; float v1 = lg[0];
    #pragma unroll
    for (int k = 1; k < E; ++k) { if (lg[k] > v1) { v1 = lg[k]; i1 = k; } }
    int i2 = -1; float v2 = -3.0e38f;
    #pragma unroll
    for (int k = 0; k < E; ++k) { if (k != i1 && lg[k] > v2) { v2 = lg[k]; i2 = k; } }

    float w1 = 1.f / (1.f + expf(v2 - v1));
    float w2 = 1.f - w1;

    if (lane == 0) {
        int p = atomicAdd(&cnt[i1], 1);
        entries[i1 * T + p] = t * 2;
        wlist[i1 * T + p] = w1;
        p = atomicAdd(&cnt[i2], 1);
        entries[i2 * T + p] = t * 2 + 1;
        wlist[i2 * T + p] = w2;
    }
}

// ------------------------------------------------------------------
// Grouped gate/up GEMM + SwiGLU.
// Block: expert e, token tile (32 gathered rows), 64 intermediate cols.
// LDS is K-major: Xs[k][row], Gs/Us[k][col] -> vectorized conflict-light reads.
// ------------------------------------------------------------------
__global__ __launch_bounds__(256) void gateup_kernel(
    const float* __restrict__ x,       // [T,H]
    const float* __restrict__ gate_p,  // [E,I,H]
    const float* __restrict__ up_p,    // [E,I,H]
    const int* __restrict__ cnt,
    const int* __restrict__ entries,
    float* __restrict__ hmid)          // [2T, I] indexed by slot = t*2+k
{
    const int e = blockIdx.z;
    const int n = cnt[e];
    const int t0 = blockIdx.x * TM;
    if (t0 >= n) return;
    const int i0 = blockIdx.y * TN;

    __shared__ float Xs[KC][XPAD];
    __shared__ float Gs[KC][WPAD];
    __shared__ float Us[KC][WPAD];
    __shared__ int toks[TM];

    const int tid = threadIdx.x;
    if (tid < TM) {
        int r = t0 + tid;
        toks[tid] = (r < n) ? entries[e * T + r] : -1;
    }
    __syncthreads();

    const int xr_ = tid >> 3, xc4 = tid & 7;      // X stage: row, f4-col
    const int ent_x = toks[xr_];
    const float* xrow = (ent_x >= 0) ? (x + (size_t)(ent_x >> 1) * H + xc4 * 4) : nullptr;
    const float* gp = gate_p + (size_t)e * I * H;
    const float* up = up_p + (size_t)e * I * H;

    float accg[4][2] = {};
    float accu[4][2] = {};
    const int ty = tid >> 5;   // 0..7 -> 4 rows each
    const int tx = tid & 31;   // 0..31 -> 2 cols each

    for (int k0 = 0; k0 < H; k0 += KC) {
        __syncthreads();
        // stage X (32 rows x 32 k)
        float4 xv = make_float4(0.f, 0.f, 0.f, 0.f);
        if (xrow) xv = *(const float4*)(xrow + k0);
        Xs[xc4 * 4 + 0][xr_] = xv.x;
        Xs[xc4 * 4 + 1][xr_] = xv.y;
        Xs[xc4 * 4 + 2][xr_] = xv.z;
        Xs[xc4 * 4 + 3][xr_] = xv.w;
        // stage G/U (64 cols x 32 k), 2 passes
        #pragma unroll
        for (int it = 0; it < 2; ++it) {
            int c = (tid >> 3) + it * 32;
            int c4 = tid & 7;
            const float* gsrc = gp + (size_t)(i0 + c) * H + k0 + c4 * 4;
            const float* usrc = up + (size_t)(i0 + c) * H + k0 + c4 * 4;
            float4 gv = *(const float4*)gsrc;
            float4 uv = *(const float4*)usrc;
            Gs[c4 * 4 + 0][c] = gv.x; Gs[c4 * 4 + 1][c] = gv.y;
            Gs[c4 * 4 + 2][c] = gv.z; Gs[c4 * 4 + 3][c] = gv.w;
            Us[c4 * 4 + 0][c] = uv.x; Us[c4 * 4 + 1][c] = uv.y;
            Us[c4 * 4 + 2][c] = uv.z; Us[c4 * 4 + 3][c] = uv.w;
        }
        __syncthreads();

        #pragma unroll
        for (int kk = 0; kk < KC; ++kk) {
            float4 a = *(const float4*)&Xs[kk][ty * 4];
            float2 g = *(const float2*)&Gs[kk][tx * 2];
            float2 u = *(const float2*)&Us[kk][tx * 2];
            float av[4] = {a.x, a.y, a.z, a.w};
            #pragma unroll
            for (int i = 0; i < 4; ++i) {
                accg[i][0] += av[i] * g.x; accg[i][1] += av[i] * g.y;
                accu[i][0] += av[i] * u.x; accu[i][1] += av[i] * u.y;
            }
        }
    }

    #pragma unroll
    for (int i = 0; i < 4; ++i) {
        int r = ty * 4 + i;
        int ent = toks[r];
        if (ent < 0) continue;
        float g0 = accg[i][0], g1 = accg[i][1];
        float2 o;
        o.x = (g0 / (1.f + expf(-g0))) * accu[i][0];
        o.y = (g1 / (1.f + expf(-g1))) * accu[i][1];
        *(float2*)(hmid + (size_t)ent * I + i0 + tx * 2) = o;
    }
}

// ------------------------------------------------------------------
// Grouped down GEMM: out[t,:] += w * (hmid[slot,:] @ down_proj[e].T)
// ------------------------------------------------------------------
__global__ __launch_bounds__(256) void down_kernel(
    const float* __restrict__ hmid,    // [2T, I]
    const float* __restrict__ down_p,  // [E, H, I]
    const int* __restrict__ cnt,
    const int* __restrict__ entries,
    const float* __restrict__ wlist,
    float* __restrict__ out)           // [T, H], pre-zeroed
{
    const int e = blockIdx.z;
    const int n = cnt[e];
    const int t0 = blockIdx.x * TM;
    if (t0 >= n) return;
    const int h0 = blockIdx.y * TN;

    __shared__ float Hs[KC][XPAD];
    __shared__ float Ds[KC][WPAD];
    __shared__ int toks[TM];
    __shared__ float wrow[TM];

    const int tid = threadIdx.x;
    if (tid < TM) {
        int r = t0 + tid;
        bool v = (r < n);
        toks[tid] = v ? entries[e * T + r] : -1;
        wrow[tid] = v ? wlist[e * T + r] : 0.f;
    }
    __syncthreads();

    const int hr = tid >> 3, hc4 = tid & 7;
    const int ent_h = toks[hr];
    const float* hrow = (ent_h >= 0) ? (hmid + (size_t)ent_h * I + hc4 * 4) : nullptr;
    const float* dp = down_p + (size_t)e * H * I;

    float acc[4][2] = {};
    const int ty = tid >> 5;
    const int tx = tid & 31;

    for (int k0 = 0; k0 < I; k0 += KC) {
        __syncthreads();
        float4 hv = make_float4(0.f, 0.f, 0.f, 0.f);
        if (hrow) hv = *(const float4*)(hrow + k0);
        Hs[hc4 * 4 + 0][hr] = hv.x;
        Hs[hc4 * 4 + 1][hr] = hv.y;
        Hs[hc4 * 4 + 2][hr] = hv.z;
        Hs[hc4 * 4 + 3][hr] = hv.w;
        #pragma unroll
        for (int it = 0; it < 2; ++it) {
            int c = (tid >> 3) + it * 32;
            int c4 = tid & 7;
            float4 dv = *(const float4*)(dp + (size_t)(h0 + c) * I + k0 + c4 * 4);
            Ds[c4 * 4 + 0][c] = dv.x; Ds[c4 * 4 + 1][c] = dv.y;
            Ds[c4 * 4 + 2][c] = dv.z; Ds[c4 * 4 + 3][c] = dv.w;
        }
        __syncthreads();

        #pragma unroll
        for (int kk = 0; kk < KC; ++kk) {
            float4 a = *(const float4*)&Hs[kk][ty * 4];
            float2 d = *(const float2*)&Ds[kk][tx * 2];
            float av[4] = {a.x, a.y, a.z, a.w};
            #pragma unroll
            for (int i = 0; i < 4; ++i) {
                acc[i][0] += av[i] * d.x;
                acc[i][1] += av[i] * d.y;
            }
        }
    }

    #pragma unroll
    for (int i = 0; i < 4; ++i) {
        int r = ty * 4 + i;
        int ent = toks[r];
        if (ent < 0) continue;
        int t = ent >> 1;
        float w = wrow[r];
        atomicAdd(&out[(size_t)t * H + h0 + tx * 2 + 0], acc[i][0] * w);
        atomicAdd(&out[(size_t)t * H + h0 + tx * 2 + 1], acc[i][1] * w);
    }
}

extern "C" void kernel_launch(void* const* d_in, const int* in_sizes, int n_in,
                              void* d_out, int out_size, void* d_ws, size_t ws_size,
                              hipStream_t stream) {
    const float* x  = (const float*)d_in[0];   // [1,2048,1024]
    const float* gw = (const float*)d_in[1];   // [16,1024]
    const float* gp = (const float*)d_in[2];   // [16,768,1024]
    const float* up = (const float*)d_in[3];   // [16,768,1024]
    const float* dp = (const float*)d_in[4];   // [16,1024,768]
    float* out = (float*)d_out;

    char* ws = (char*)d_ws;
    int*   cnt     = (int*)ws;                          // E ints
    int*   entries = (int*)(ws + 256);                  // E*T ints
    float* wlist   = (float*)(ws + 256 + E * T * 4);    // E*T floats
    float* hmid    = (float*)(ws + 256 + E * T * 8);    // 2T*I floats (~12.6 MB)

    hipMemsetAsync(cnt, 0, E * sizeof(int), stream);
    hipMemsetAsync(out, 0, (size_t)T * H * sizeof(float), stream);

    router_kernel<<<T / 4, 256, 0, stream>>>(x, gw, cnt, entries, wlist);
    gateup_kernel<<<dim3(T / TM, I / TN, E), 256, 0, stream>>>(x, gp, up, cnt, entries, hmid);
    down_kernel<<<dim3(T / TM, H / TN, E), 256, 0, stream>>>(hmid, dp, cnt, entries, wlist, out);
}

// Round 2
// 593.397 us; speedup vs baseline: 2.1964x; 2.1964x over previous
//
#include <hip/hip_runtime.h>
#include <hip/hip_bf16.h>
#include <cmath>

// Problem constants (Qwen3 MoE block)
constexpr int T = 2048;   // tokens (B*S)
constexpr int H = 1024;   // hidden
constexpr int I = 768;    // intermediate
constexpr int E = 16;     // experts

typedef short short8 __attribute__((ext_vector_type(8)));
typedef float f32x4  __attribute__((ext_vector_type(4)));

__device__ __forceinline__ short f2bf(float f) {
    __hip_bfloat16 h = __float2bfloat16(f);   // RNE
    return *reinterpret_cast<short*>(&h);
}

// XOR-swizzled LDS index (units: shorts). Row stride 32 bf16 = 64 B.
// Slot permutation ((kg + (r>>1)) & 3) spreads 16-B slots so both the
// 16-row staging writes and the m16/quad fragment reads hit all 8
// bank-window positions evenly -> conflict-free b128 traffic.
__device__ __forceinline__ int sw(int r, int kg) {
    return r * 32 + (((kg + (r >> 1)) & 3) << 3);
}

// ------------------------------------------------------------------
// x fp32 -> bf16 (done once; x is re-read by 6 N-tiles in gateup)
// ------------------------------------------------------------------
__global__ __launch_bounds__(256) void cvt_x_kernel(
    const float* __restrict__ x, short* __restrict__ xb)
{
    int i = blockIdx.x * 256 + threadIdx.x;      // one short8 per thread
    const float4* src = (const float4*)x;
    float4 a = src[2 * i], b = src[2 * i + 1];
    short8 v = {f2bf(a.x), f2bf(a.y), f2bf(a.z), f2bf(a.w),
                f2bf(b.x), f2bf(b.y), f2bf(b.z), f2bf(b.w)};
    *(short8*)(xb + (size_t)i * 8) = v;
}

// ------------------------------------------------------------------
// Router: one wave per token. 16 logits -> top2 -> renormalized probs.
// Renormalized top-2 softmax == softmax over the two winning logits.
// ------------------------------------------------------------------
__global__ __launch_bounds__(256) void router_kernel(
    const float* __restrict__ x,     // [T,H]
    const float* __restrict__ gw,    // [E,H]
    int* __restrict__ cnt,           // [E]
    int* __restrict__ entries,       // [E,T]  value = t*2 + k
    float* __restrict__ wlist)       // [E,T]
{
    const int wave = threadIdx.x >> 6;
    const int lane = threadIdx.x & 63;
    const int t = blockIdx.x * 4 + wave;
    const int e = lane >> 2;         // 4 lanes per expert
    const int part = lane & 3;

    const float4* xr = (const float4*)(x + (size_t)t * H);
    const float4* gr = (const float4*)(gw + (size_t)e * H);
    float s = 0.f;
    #pragma unroll 8
    for (int q = 0; q < 64; ++q) {
        float4 a = xr[part * 64 + q];
        float4 b = gr[part * 64 + q];
        s += a.x * b.x + a.y * b.y + a.z * b.z + a.w * b.w;
    }
    s += __shfl_xor(s, 1);
    s += __shfl_xor(s, 2);

    float lg[E];
    #pragma unroll
    for (int k = 0; k < E; ++k) lg[k] = __shfl(s, k * 4);

    int i1 = 0; float v1 = lg[0];
    #pragma unroll
    for (int k = 1; k < E; ++k) { if (lg[k] > v1) { v1 = lg[k]; i1 = k; } }
    int i2 = -1; float v2 = -3.0e38f;
    #pragma unroll
    for (int k = 0; k < E; ++k) { if (k != i1 && lg[k] > v2) { v2 = lg[k]; i2 = k; } }

    float w1 = 1.f / (1.f + expf(v2 - v1));
    float w2 = 1.f - w1;

    if (lane == 0) {
        int p = atomicAdd(&cnt[i1], 1);
        entries[i1 * T + p] = t * 2;
        wlist[i1 * T + p] = w1;
        p = atomicAdd(&cnt[i2], 1);
        entries[i2 * T + p] = t * 2 + 1;
        wlist[i2 * T + p] = w2;
    }
}

// ------------------------------------------------------------------
// Grouped gate/up GEMM + SwiGLU, bf16 MFMA.
// Block: 4 waves, tile M=64 gathered tokens x N=128 intermediate cols.
// Each wave computes a 64x32 tile of BOTH gate and up -> SwiGLU is
// wave-local. Weights converted f32->bf16 during LDS staging.
// ------------------------------------------------------------------
__global__ __launch_bounds__(256) void gateup_mfma(
    const short* __restrict__ xb,      // [T,H] bf16
    const float* __restrict__ gate_p,  // [E,I,H] f32
    const float* __restrict__ up_p,    // [E,I,H] f32
    const int* __restrict__ cnt,
    const int* __restrict__ entries,
    short* __restrict__ hmid)          // [2T,I] bf16, row = slot = t*2+k
{
    const int e = blockIdx.z;
    const int n = cnt[e];
    const int t0 = blockIdx.x * 64;
    if (t0 >= n) return;
    const int i0 = blockIdx.y * 128;

    __shared__ short Xs[64 * 32];
    __shared__ short Gs[128 * 32];
    __shared__ short Us[128 * 32];
    __shared__ int toks[64];

    const int tid = threadIdx.x;
    if (tid < 64) {
        int r = t0 + tid;
        toks[tid] = (r < n) ? entries[e * T + r] : -1;
    }
    __syncthreads();

    const int lane = tid & 63, wave = tid >> 6;
    const int m16 = lane & 15, q = lane >> 4;

    const float* gpe = gate_p + (size_t)e * I * H;
    const float* upe = up_p   + (size_t)e * I * H;

    f32x4 accg[4][2], accu[4][2];
    #pragma unroll
    for (int a = 0; a < 4; ++a)
        #pragma unroll
        for (int b = 0; b < 2; ++b) {
            accg[a][b] = (f32x4){0.f, 0.f, 0.f, 0.f};
            accu[a][b] = (f32x4){0.f, 0.f, 0.f, 0.f};
        }

    // staging coords: X -> one 16B slot/thread; G,U -> two slots each
    const int sr = tid >> 2, skg = tid & 3;
    const int xtok = toks[sr];
    const short* xsrc = (xtok >= 0) ? (xb + (size_t)(xtok >> 1) * H + skg * 8) : nullptr;

    for (int k0 = 0; k0 < H; k0 += 32) {
        __syncthreads();
        short8 xv = {0, 0, 0, 0, 0, 0, 0, 0};
        if (xsrc) xv = *(const short8*)(xsrc + k0);
        *(short8*)&Xs[sw(sr, skg)] = xv;

        #pragma unroll
        for (int t2 = 0; t2 < 2; ++t2) {
            int s = tid + t2 * 256;
            int r = s >> 2, kg = s & 3;
            const float* g8 = gpe + (size_t)(i0 + r) * H + k0 + kg * 8;
            const float* u8 = upe + (size_t)(i0 + r) * H + k0 + kg * 8;
            float4 ga = *(const float4*)g8, gb = *(const float4*)(g8 + 4);
            float4 ua = *(const float4*)u8, ub = *(const float4*)(u8 + 4);
            short8 gv = {f2bf(ga.x), f2bf(ga.y), f2bf(ga.z), f2bf(ga.w),
                         f2bf(gb.x), f2bf(gb.y), f2bf(gb.z), f2bf(gb.w)};
            short8 uv = {f2bf(ua.x), f2bf(ua.y), f2bf(ua.z), f2bf(ua.w),
                         f2bf(ub.x), f2bf(ub.y), f2bf(ub.z), f2bf(ub.w)};
            *(short8*)&Gs[sw(r, kg)] = gv;
            *(short8*)&Us[sw(r, kg)] = uv;
        }
        __syncthreads();

        short8 af[4];
        #pragma unroll
        for (int mi = 0; mi < 4; ++mi)
            af[mi] = *(const short8*)&Xs[sw(mi * 16 + m16, q)];
        #pragma unroll
        for (int ni = 0; ni < 2; ++ni) {
            int wc = wave * 32 + ni * 16 + m16;
            short8 bg = *(const short8*)&Gs[sw(wc, q)];
            short8 bu = *(const short8*)&Us[sw(wc, q)];
            #pragma unroll
            for (int mi = 0; mi < 4; ++mi) {
                accg[mi][ni] = __builtin_amdgcn_mfma_f32_16x16x32_bf16(af[mi], bg, accg[mi][ni], 0, 0, 0);
                accu[mi][ni] = __builtin_amdgcn_mfma_f32_16x16x32_bf16(af[mi], bu, accu[mi][ni], 0, 0, 0);
            }
        }
    }

    // epilogue: SwiGLU wave-local, scalar bf16 stores
    #pragma unroll
    for (int mi = 0; mi < 4; ++mi)
        #pragma unroll
        for (int ni = 0; ni < 2; ++ni)
            #pragma unroll
            for (int j = 0; j < 4; ++j) {
                int row = mi * 16 + q * 4 + j;
                int slot = toks[row];
                if (slot < 0) continue;
                float g = accg[mi][ni][j];
                float u = accu[mi][ni][j];
                float hv = g / (1.f + expf(-g)) * u;
                int col = i0 + wave * 32 + ni * 16 + m16;
                ((unsigned short*)hmid)[(size_t)slot * I + col] = (unsigned short)f2bf(hv);
            }
}

// ------------------------------------------------------------------
// Grouped down GEMM, bf16 MFMA.
// Block: M=64 gathered slots x N=256 hidden cols; wave tile 64x64.
// Combine via f32 atomicAdd (exactly 2 adds per out element).
// ------------------------------------------------------------------
__global__ __launch_bounds__(256) void down_mfma(
    const short* __restrict__ hmid,    // [2T,I] bf16
    const float* __restrict__ down_p,  // [E,H,I] f32
    const int* __restrict__ cnt,
    const int* __restrict__ entries,
    const float* __restrict__ wlist,
    float* __restrict__ out)           // [T,H], pre-zeroed
{
    const int e = blockIdx.z;
    const int n = cnt[e];
    const int t0 = blockIdx.x * 64;
    if (t0 >= n) return;
    const int h0 = blockIdx.y * 256;

    __shared__ short As[64 * 32];
    __shared__ short Bs[256 * 32];
    __shared__ int toks[64];
    __shared__ float wr[64];

    const int tid = threadIdx.x;
    if (tid < 64) {
        int r = t0 + tid;
        bool v = (r < n);
        toks[tid] = v ? entries[e * T + r] : -1;
        wr[tid]   = v ? wlist[e * T + r] : 0.f;
    }
    __syncthreads();

    const int lane = tid & 63, wave = tid >> 6;
    const int m16 = lane & 15, q = lane >> 4;

    const float* dpe = down_p + (size_t)e * H * I;

    f32x4 acc[4][4];
    #pragma unroll
    for (int a = 0; a < 4; ++a)
        #pragma unroll
        for (int b = 0; b < 4; ++b)
            acc[a][b] = (f32x4){0.f, 0.f, 0.f, 0.f};

    const int sr = tid >> 2, skg = tid & 3;
    const int aslot = toks[sr];
    const short* asrc = (aslot >= 0) ? (hmid + (size_t)aslot * I + skg * 8) : nullptr;

    for (int k0 = 0; k0 < I; k0 += 32) {
        __syncthreads();
        short8 av = {0, 0, 0, 0, 0, 0, 0, 0};
        if (asrc) av = *(const short8*)(asrc + k0);
        *(short8*)&As[sw(sr, skg)] = av;

        #pragma unroll
        for (int t4 = 0; t4 < 4; ++t4) {
            int s = tid + t4 * 256;
            int r = s >> 2, kg = s & 3;
            const float* d8 = dpe + (size_t)(h0 + r) * I + k0 + kg * 8;
            float4 da = *(const float4*)d8, db = *(const float4*)(d8 + 4);
            short8 dv = {f2bf(da.x), f2bf(da.y), f2bf(da.z), f2bf(da.w),
                         f2bf(db.x), f2bf(db.y), f2bf(db.z), f2bf(db.w)};
            *(short8*)&Bs[sw(r, kg)] = dv;
        }
        __syncthreads();

        short8 af[4];
        #pragma unroll
        for (int mi = 0; mi < 4; ++mi)
            af[mi] = *(const short8*)&As[sw(mi * 16 + m16, q)];
        #pragma unroll
        for (int ni = 0; ni < 4; ++ni) {
            short8 bfr = *(const short8*)&Bs[sw(wave * 64 + ni * 16 + m16, q)];
            #pragma unroll
            for (int mi = 0; mi < 4; ++mi)
                acc[mi][ni] = __builtin_amdgcn_mfma_f32_16x16x32_bf16(af[mi], bfr, acc[mi][ni], 0, 0, 0);
        }
    }

    #pragma unroll
    for (int mi = 0; mi < 4; ++mi)
        #pragma unroll
        for (int ni = 0; ni < 4; ++ni)
            #pragma unroll
            for (int j = 0; j < 4; ++j) {
                int row = mi * 16 + q * 4 + j;
                int slot = toks[row];
                if (slot < 0) continue;
                int t = slot >> 1;
                float w = wr[row];
                int col = h0 + wave * 64 + ni * 16 + m16;
                atomicAdd(&out[(size_t)t * H + col], w * acc[mi][ni][j]);
            }
}

extern "C" void kernel_launch(void* const* d_in, const int* in_sizes, int n_in,
                              void* d_out, int out_size, void* d_ws, size_t ws_size,
                              hipStream_t stream) {
    const float* x  = (const float*)d_in[0];   // [1,2048,1024]
    const float* gw = (const float*)d_in[1];   // [16,1024]
    const float* gp = (const float*)d_in[2];   // [16,768,1024]
    const float* up = (const float*)d_in[3];   // [16,768,1024]
    const float* dp = (const float*)d_in[4];   // [16,1024,768]
    float* out = (float*)d_out;

    char* ws = (char*)d_ws;
    int*   cnt     = (int*)ws;                               // 256 B reserved
    int*   entries = (int*)(ws + 256);                       // E*T ints
    float* wlist   = (float*)(ws + 256 + E * T * 4);         // E*T floats
    short* xb      = (short*)(ws + 256 + E * T * 8);         // T*H bf16 (4 MB)
    short* hmid    = (short*)(ws + 256 + E * T * 8 + (size_t)T * H * 2); // 2T*I bf16 (6 MB)

    hipMemsetAsync(cnt, 0, E * sizeof(int), stream);
    hipMemsetAsync(out, 0, (size_t)T * H * sizeof(float), stream);

    cvt_x_kernel<<<(T * H / 8) / 256, 256, 0, stream>>>(x, xb);
    router_kernel<<<T / 4, 256, 0, stream>>>(x, gw, cnt, entries, wlist);
    gateup_mfma<<<dim3(T / 64, I / 128, E), 256, 0, stream>>>(xb, gp, up, cnt, entries, hmid);
    down_mfma<<<dim3(T / 64, H / 256, E), 256, 0, stream>>>(hmid, dp, cnt, entries, wlist, out);
}

// Round 3
// 347.066 us; speedup vs baseline: 3.7552x; 1.7098x over previous
//
#include <hip/hip_runtime.h>
#include <hip/hip_bf16.h>
#include <cmath>

// Problem constants (Qwen3 MoE block)
constexpr int T = 2048;   // tokens (B*S)
constexpr int H = 1024;   // hidden
constexpr int I = 768;    // intermediate
constexpr int E = 16;     // experts
constexpr int WMAX = 96;  // work-item grid cap (true max = 4096/64+16 = 80)

typedef short short8 __attribute__((ext_vector_type(8)));
typedef float f32x4  __attribute__((ext_vector_type(4)));

__device__ __forceinline__ short f2bf(float f) {
    __hip_bfloat16 h = __float2bfloat16(f);   // RNE
    return *reinterpret_cast<short*>(&h);
}

// XOR-swizzled LDS index (units: shorts). Row stride 32 bf16 = 64 B.
// Physical 16-B slot = ((kg + (r>>1)) & 3). Round 2 measured 0 bank conflicts.
__device__ __forceinline__ int sw(int r, int kg) {
    return r * 32 + (((kg + (r >> 1)) & 3) << 3);
}

// Async global->LDS, 16 B per lane. LDS dest must be wave-uniform base;
// lane i lands at base + i*16 B. Global addr is per-lane.
__device__ __forceinline__ void gll16(const void* g, void* l) {
    __builtin_amdgcn_global_load_lds(
        (const __attribute__((address_space(1))) unsigned int*)g,
        (__attribute__((address_space(3))) unsigned int*)l,
        16, 0, 0);
}

// ------------------------------------------------------------------
// fp32 -> bf16 bulk convert (x and, when ws allows, the three weights)
// ------------------------------------------------------------------
__global__ __launch_bounds__(256) void cvt_kernel(
    const float* __restrict__ src, short* __restrict__ dst)
{
    size_t i = (size_t)blockIdx.x * 256 + threadIdx.x;   // one short8 per thread
    const float4* s4 = (const float4*)src;
    float4 a = s4[2 * i], b = s4[2 * i + 1];
    short8 v = {f2bf(a.x), f2bf(a.y), f2bf(a.z), f2bf(a.w),
                f2bf(b.x), f2bf(b.y), f2bf(b.z), f2bf(b.w)};
    *(short8*)(dst + i * 8) = v;
}

// ------------------------------------------------------------------
// Router: one wave per token. 16 logits -> top2 -> renormalized probs.
// ------------------------------------------------------------------
__global__ __launch_bounds__(256) void router_kernel(
    const float* __restrict__ x,     // [T,H]
    const float* __restrict__ gw,    // [E,H]
    int* __restrict__ cnt,           // [E]
    int* __restrict__ entries,       // [E,T]  value = t*2 + k
    float* __restrict__ wlist)       // [E,T]
{
    const int wave = threadIdx.x >> 6;
    const int lane = threadIdx.x & 63;
    const int t = blockIdx.x * 4 + wave;
    const int e = lane >> 2;         // 4 lanes per expert
    const int part = lane & 3;

    const float4* xr = (const float4*)(x + (size_t)t * H);
    const float4* gr = (const float4*)(gw + (size_t)e * H);
    float s = 0.f;
    #pragma unroll 8
    for (int q = 0; q < 64; ++q) {
        float4 a = xr[part * 64 + q];
        float4 b = gr[part * 64 + q];
        s += a.x * b.x + a.y * b.y + a.z * b.z + a.w * b.w;
    }
    s += __shfl_xor(s, 1);
    s += __shfl_xor(s, 2);

    float lg[E];
    #pragma unroll
    for (int k = 0; k < E; ++k) lg[k] = __shfl(s, k * 4);

    int i1 = 0; float v1 = lg[0];
    #pragma unroll
    for (int k = 1; k < E; ++k) { if (lg[k] > v1) { v1 = lg[k]; i1 = k; } }
    int i2 = -1; float v2 = -3.0e38f;
    #pragma unroll
    for (int k = 0; k < E; ++k) { if (k != i1 && lg[k] > v2) { v2 = lg[k]; i2 = k; } }

    float w1 = 1.f / (1.f + expf(v2 - v1));
    float w2 = 1.f - w1;

    if (lane == 0) {
        int p = atomicAdd(&cnt[i1], 1);
        entries[i1 * T + p] = t * 2;
        wlist[i1 * T + p] = w1;
        p = atomicAdd(&cnt[i2], 1);
        entries[i2 * T + p] = t * 2 + 1;
        wlist[i2 * T + p] = w2;
    }
}

// ------------------------------------------------------------------
// Work-list builder: flat (expert, t0) items so every GEMM block is live.
// ------------------------------------------------------------------
__global__ void build_worklist(const int* __restrict__ cnt,
                               int2* __restrict__ items,
                               int* __restrict__ nitems)
{
    if (threadIdx.x == 0) {
        int c = 0;
        for (int e = 0; e < E; ++e) {
            int n = cnt[e];
            for (int t0 = 0; t0 < n; t0 += 64) items[c++] = make_int2(e, t0);
        }
        *nitems = c;
    }
}

// ------------------------------------------------------------------
// Grouped gate/up GEMM + SwiGLU, bf16 MFMA, async DMA staging.
// Tile M=64 gathered tokens x N=128 intermediate; wave owns 64x32 of
// BOTH gate and up -> SwiGLU wave-local.
// ------------------------------------------------------------------
__global__ __launch_bounds__(256) void gateup_mfma_dma(
    const short* __restrict__ xb,      // [T,H] bf16
    const short* __restrict__ gpb,     // [E,I,H] bf16
    const short* __restrict__ upb,     // [E,I,H] bf16
    const int* __restrict__ cnt,
    const int* __restrict__ entries,
    const int* __restrict__ nitems,
    const int2* __restrict__ items,
    short* __restrict__ hmid)          // [2T,I] bf16, row = slot
{
    if (blockIdx.x >= *nitems) return;
    const int e  = items[blockIdx.x].x;
    const int t0 = items[blockIdx.x].y;
    const int n  = cnt[e];
    const int i0 = blockIdx.y * 128;

    __shared__ short Xs[64 * 32];
    __shared__ short Gs[128 * 32];
    __shared__ short Us[128 * 32];
    __shared__ int toks[64];

    const int tid = threadIdx.x;
    if (tid < 64) {
        int r = t0 + tid;
        toks[tid] = (r < n) ? entries[e * T + r] : -1;
    }
    __syncthreads();

    const int lane = tid & 63, wave = tid >> 6;
    const int m16 = lane & 15, q = lane >> 4;
    const int rr = lane >> 2;          // row within 16-row DMA chunk
    const int p  = lane & 3;           // physical 16-B slot

    // X staging: wave w covers tile rows w*16..w*16+15 (gathered)
    const int xrow = wave * 16 + rr;
    const int xtok = toks[xrow];
    const int xkg  = (p - (xrow >> 1)) & 3;   // source kg for swizzled slot
    const short* xsrc = xb + (size_t)((xtok >= 0 ? xtok : 0) >> 1) * H + xkg * 8;

    // G/U staging: wave w covers chunks w and w+4 (rows c*16+rr of 128)
    const size_t wbase = (size_t)e * I * H;
    const int gr0 = wave * 16 + rr, gr1 = (wave + 4) * 16 + rr;
    const int gk0 = (p - (gr0 >> 1)) & 3, gk1 = (p - (gr1 >> 1)) & 3;
    const short* gsrc0 = gpb + wbase + (size_t)(i0 + gr0) * H + gk0 * 8;
    const short* gsrc1 = gpb + wbase + (size_t)(i0 + gr1) * H + gk1 * 8;
    const short* usrc0 = upb + wbase + (size_t)(i0 + gr0) * H + gk0 * 8;
    const short* usrc1 = upb + wbase + (size_t)(i0 + gr1) * H + gk1 * 8;

    f32x4 accg[4][2], accu[4][2];
    #pragma unroll
    for (int a = 0; a < 4; ++a)
        #pragma unroll
        for (int b = 0; b < 2; ++b) {
            accg[a][b] = (f32x4){0.f, 0.f, 0.f, 0.f};
            accu[a][b] = (f32x4){0.f, 0.f, 0.f, 0.f};
        }

    for (int k0 = 0; k0 < H; k0 += 32) {
        __syncthreads();
        gll16(xsrc + k0,  &Xs[wave * 512]);
        gll16(gsrc0 + k0, &Gs[wave * 512]);
        gll16(gsrc1 + k0, &Gs[(wave + 4) * 512]);
        gll16(usrc0 + k0, &Us[wave * 512]);
        gll16(usrc1 + k0, &Us[(wave + 4) * 512]);
        __syncthreads();   // barrier drains vmcnt -> DMA complete

        short8 af[4];
        #pragma unroll
        for (int mi = 0; mi < 4; ++mi)
            af[mi] = *(const short8*)&Xs[sw(mi * 16 + m16, q)];
        #pragma unroll
        for (int ni = 0; ni < 2; ++ni) {
            int wc = wave * 32 + ni * 16 + m16;
            short8 bg = *(const short8*)&Gs[sw(wc, q)];
            short8 bu = *(const short8*)&Us[sw(wc, q)];
            #pragma unroll
            for (int mi = 0; mi < 4; ++mi) {
                accg[mi][ni] = __builtin_amdgcn_mfma_f32_16x16x32_bf16(af[mi], bg, accg[mi][ni], 0, 0, 0);
                accu[mi][ni] = __builtin_amdgcn_mfma_f32_16x16x32_bf16(af[mi], bu, accu[mi][ni], 0, 0, 0);
            }
        }
    }

    #pragma unroll
    for (int mi = 0; mi < 4; ++mi)
        #pragma unroll
        for (int ni = 0; ni < 2; ++ni)
            #pragma unroll
            for (int j = 0; j < 4; ++j) {
                int row = mi * 16 + q * 4 + j;
                int slot = toks[row];
                if (slot < 0) continue;
                float g = accg[mi][ni][j];
                float u = accu[mi][ni][j];
                float hv = g / (1.f + expf(-g)) * u;
                int col = i0 + wave * 32 + ni * 16 + m16;
                ((unsigned short*)hmid)[(size_t)slot * I + col] = (unsigned short)f2bf(hv);
            }
}

// ------------------------------------------------------------------
// Grouped down GEMM, bf16 MFMA, async DMA staging.
// Tile M=64 slots x N=256 hidden; wave tile 64x64. f32 atomic combine.
// ------------------------------------------------------------------
__global__ __launch_bounds__(256) void down_mfma_dma(
    const short* __restrict__ hmid,    // [2T,I] bf16
    const short* __restrict__ dpb,     // [E,H,I] bf16
    const int* __restrict__ cnt,
    const int* __restrict__ entries,
    const float* __restrict__ wlist,
    const int* __restrict__ nitems,
    const int2* __restrict__ items,
    float* __restrict__ out)           // [T,H], pre-zeroed
{
    if (blockIdx.x >= *nitems) return;
    const int e  = items[blockIdx.x].x;
    const int t0 = items[blockIdx.x].y;
    const int n  = cnt[e];
    const int h0 = blockIdx.y * 256;

    __shared__ short As[64 * 32];
    __shared__ short Bs[256 * 32];
    __shared__ int toks[64];
    __shared__ float wr[64];

    const int tid = threadIdx.x;
    if (tid < 64) {
        int r = t0 + tid;
        bool v = (r < n);
        toks[tid] = v ? entries[e * T + r] : -1;
        wr[tid]   = v ? wlist[e * T + r] : 0.f;
    }
    __syncthreads();

    const int lane = tid & 63, wave = tid >> 6;
    const int m16 = lane & 15, q = lane >> 4;
    const int rr = lane >> 2, p = lane & 3;

    const int arow = wave * 16 + rr;
    const int aslot = toks[arow];
    const int akg = (p - (arow >> 1)) & 3;
    const short* asrc = hmid + (size_t)(aslot >= 0 ? aslot : 0) * I + akg * 8;

    const size_t wbase = (size_t)e * H * I;
    const short* bsrc[4];
    int bchunk[4];
    #pragma unroll
    for (int j = 0; j < 4; ++j) {
        int c = wave + j * 4;          // chunks w, w+4, w+8, w+12
        int r = c * 16 + rr;
        int kg = (p - (r >> 1)) & 3;
        bchunk[j] = c;
        bsrc[j] = dpb + wbase + (size_t)(h0 + r) * I + kg * 8;
    }

    f32x4 acc[4][4];
    #pragma unroll
    for (int a = 0; a < 4; ++a)
        #pragma unroll
        for (int b = 0; b < 4; ++b)
            acc[a][b] = (f32x4){0.f, 0.f, 0.f, 0.f};

    for (int k0 = 0; k0 < I; k0 += 32) {
        __syncthreads();
        gll16(asrc + k0, &As[wave * 512]);
        #pragma unroll
        for (int j = 0; j < 4; ++j)
            gll16(bsrc[j] + k0, &Bs[bchunk[j] * 512]);
        __syncthreads();

        short8 af[4];
        #pragma unroll
        for (int mi = 0; mi < 4; ++mi)
            af[mi] = *(const short8*)&As[sw(mi * 16 + m16, q)];
        #pragma unroll
        for (int ni = 0; ni < 4; ++ni) {
            short8 bfr = *(const short8*)&Bs[sw(wave * 64 + ni * 16 + m16, q)];
            #pragma unroll
            for (int mi = 0; mi < 4; ++mi)
                acc[mi][ni] = __builtin_amdgcn_mfma_f32_16x16x32_bf16(af[mi], bfr, acc[mi][ni], 0, 0, 0);
        }
    }

    #pragma unroll
    for (int mi = 0; mi < 4; ++mi)
        #pragma unroll
        for (int ni = 0; ni < 4; ++ni)
            #pragma unroll
            for (int j = 0; j < 4; ++j) {
                int row = mi * 16 + q * 4 + j;
                int slot = toks[row];
                if (slot < 0) continue;
                int t = slot >> 1;
                float w = wr[row];
                int col = h0 + wave * 64 + ni * 16 + m16;
                atomicAdd(&out[(size_t)t * H + col], w * acc[mi][ni][j]);
            }
}

// ------------------------------------------------------------------
// Fallback GEMMs (fp32 weights, convert during staging) for small ws.
// Same work-list distribution fix; round-2 staging otherwise.
// ------------------------------------------------------------------
__global__ __launch_bounds__(256) void gateup_mfma_f32(
    const short* __restrict__ xb,
    const float* __restrict__ gate_p,
    const float* __restrict__ up_p,
    const int* __restrict__ cnt,
    const int* __restrict__ entries,
    const int* __restrict__ nitems,
    const int2* __restrict__ items,
    short* __restrict__ hmid)
{
    if (blockIdx.x >= *nitems) return;
    const int e  = items[blockIdx.x].x;
    const int t0 = items[blockIdx.x].y;
    const int n  = cnt[e];
    const int i0 = blockIdx.y * 128;

    __shared__ short Xs[64 * 32];
    __shared__ short Gs[128 * 32];
    __shared__ short Us[128 * 32];
    __shared__ int toks[64];

    const int tid = threadIdx.x;
    if (tid < 64) {
        int r = t0 + tid;
        toks[tid] = (r < n) ? entries[e * T + r] : -1;
    }
    __syncthreads();

    const int lane = tid & 63, wave = tid >> 6;
    const int m16 = lane & 15, q = lane >> 4;

    const float* gpe = gate_p + (size_t)e * I * H;
    const float* upe = up_p   + (size_t)e * I * H;

    f32x4 accg[4][2], accu[4][2];
    #pragma unroll
    for (int a = 0; a < 4; ++a)
        #pragma unroll
        for (int b = 0; b < 2; ++b) {
            accg[a][b] = (f32x4){0.f, 0.f, 0.f, 0.f};
            accu[a][b] = (f32x4){0.f, 0.f, 0.f, 0.f};
        }

    const int sr = tid >> 2, skg = tid & 3;
    const int xtok = toks[sr];
    const short* xsrc = (xtok >= 0) ? (xb + (size_t)(xtok >> 1) * H + skg * 8) : nullptr;

    for (int k0 = 0; k0 < H; k0 += 32) {
        __syncthreads();
        short8 xv = {0, 0, 0, 0, 0, 0, 0, 0};
        if (xsrc) xv = *(const short8*)(xsrc + k0);
        *(short8*)&Xs[sw(sr, skg)] = xv;

        #pragma unroll
        for (int t2 = 0; t2 < 2; ++t2) {
            int s = tid + t2 * 256;
            int r = s >> 2, kg = s & 3;
            const float* g8 = gpe + (size_t)(i0 + r) * H + k0 + kg * 8;
            const float* u8 = upe + (size_t)(i0 + r) * H + k0 + kg * 8;
            float4 ga = *(const float4*)g8, gb = *(const float4*)(g8 + 4);
            float4 ua = *(const float4*)u8, ub = *(const float4*)(u8 + 4);
            short8 gv = {f2bf(ga.x), f2bf(ga.y), f2bf(ga.z), f2bf(ga.w),
                         f2bf(gb.x), f2bf(gb.y), f2bf(gb.z), f2bf(gb.w)};
            short8 uv = {f2bf(ua.x), f2bf(ua.y), f2bf(ua.z), f2bf(ua.w),
                         f2bf(ub.x), f2bf(ub.y), f2bf(ub.z), f2bf(ub.w)};
            *(short8*)&Gs[sw(r, kg)] = gv;
            *(short8*)&Us[sw(r, kg)] = uv;
        }
        __syncthreads();

        short8 af[4];
        #pragma unroll
        for (int mi = 0; mi < 4; ++mi)
            af[mi] = *(const short8*)&Xs[sw(mi * 16 + m16, q)];
        #pragma unroll
        for (int ni = 0; ni < 2; ++ni) {
            int wc = wave * 32 + ni * 16 + m16;
            short8 bg = *(const short8*)&Gs[sw(wc, q)];
            short8 bu = *(const short8*)&Us[sw(wc, q)];
            #pragma unroll
            for (int mi = 0; mi < 4; ++mi) {
                accg[mi][ni] = __builtin_amdgcn_mfma_f32_16x16x32_bf16(af[mi], bg, accg[mi][ni], 0, 0, 0);
                accu[mi][ni] = __builtin_amdgcn_mfma_f32_16x16x32_bf16(af[mi], bu, accu[mi][ni], 0, 0, 0);
            }
        }
    }

    #pragma unroll
    for (int mi = 0; mi < 4; ++mi)
        #pragma unroll
        for (int ni = 0; ni < 2; ++ni)
            #pragma unroll
            for (int j = 0; j < 4; ++j) {
                int row = mi * 16 + q * 4 + j;
                int slot = toks[row];
                if (slot < 0) continue;
                float g = accg[mi][ni][j];
                float u = accu[mi][ni][j];
                float hv = g / (1.f + expf(-g)) * u;
                int col = i0 + wave * 32 + ni * 16 + m16;
                ((unsigned short*)hmid)[(size_t)slot * I + col] = (unsigned short)f2bf(hv);
            }
}

__global__ __launch_bounds__(256) void down_mfma_f32(
    const short* __restrict__ hmid,
    const float* __restrict__ down_p,
    const int* __restrict__ cnt,
    const int* __restrict__ entries,
    const float* __restrict__ wlist,
    const int* __restrict__ nitems,
    const int2* __restrict__ items,
    float* __restrict__ out)
{
    if (blockIdx.x >= *nitems) return;
    const int e  = items[blockIdx.x].x;
    const int t0 = items[blockIdx.x].y;
    const int n  = cnt[e];
    const int h0 = blockIdx.y * 256;

    __shared__ short As[64 * 32];
    __shared__ short Bs[256 * 32];
    __shared__ int toks[64];
    __shared__ float wr[64];

    const int tid = threadIdx.x;
    if (tid < 64) {
        int r = t0 + tid;
        bool v = (r < n);
        toks[tid] = v ? entries[e * T + r] : -1;
        wr[tid]   = v ? wlist[e * T + r] : 0.f;
    }
    __syncthreads();

    const int lane = tid & 63, wave = tid >> 6;
    const int m16 = lane & 15, q = lane >> 4;

    const float* dpe = down_p + (size_t)e * H * I;

    f32x4 acc[4][4];
    #pragma unroll
    for (int a = 0; a < 4; ++a)
        #pragma unroll
        for (int b = 0; b < 4; ++b)
            acc[a][b] = (f32x4){0.f, 0.f, 0.f, 0.f};

    const int sr = tid >> 2, skg = tid & 3;
    const int aslot = toks[sr];
    const short* asrc = (aslot >= 0) ? (hmid + (size_t)aslot * I + skg * 8) : nullptr;

    for (int k0 = 0; k0 < I; k0 += 32) {
        __syncthreads();
        short8 av = {0, 0, 0, 0, 0, 0, 0, 0};
        if (asrc) av = *(const short8*)(asrc + k0);
        *(short8*)&As[sw(sr, skg)] = av;

        #pragma unroll
        for (int t4 = 0; t4 < 4; ++t4) {
            int s = tid + t4 * 256;
            int r = s >> 2, kg = s & 3;
            const float* d8 = dpe + (size_t)(h0 + r) * I + k0 + kg * 8;
            float4 da = *(const float4*)d8, db = *(const float4*)(d8 + 4);
            short8 dv = {f2bf(da.x), f2bf(da.y), f2bf(da.z), f2bf(da.w),
                         f2bf(db.x), f2bf(db.y), f2bf(db.z), f2bf(db.w)};
            *(short8*)&Bs[sw(r, kg)] = dv;
        }
        __syncthreads();

        short8 af[4];
        #pragma unroll
        for (int mi = 0; mi < 4; ++mi)
            af[mi] = *(const short8*)&As[sw(mi * 16 + m16, q)];
        #pragma unroll
        for (int ni = 0; ni < 4; ++ni) {
            short8 bfr = *(const short8*)&Bs[sw(wave * 64 + ni * 16 + m16, q)];
            #pragma unroll
            for (int mi = 0; mi < 4; ++mi)
                acc[mi][ni] = __builtin_amdgcn_mfma_f32_16x16x32_bf16(af[mi], bfr, acc[mi][ni], 0, 0, 0);
        }
    }

    #pragma unroll
    for (int mi = 0; mi < 4; ++mi)
        #pragma unroll
        for (int ni = 0; ni < 4; ++ni)
            #pragma unroll
            for (int j = 0; j < 4; ++j) {
                int row = mi * 16 + q * 4 + j;
                int slot = toks[row];
                if (slot < 0) continue;
                int t = slot >> 1;
                float w = wr[row];
                int col = h0 + wave * 64 + ni * 16 + m16;
                atomicAdd(&out[(size_t)t * H + col], w * acc[mi][ni][j]);
            }
}

extern "C" void kernel_launch(void* const* d_in, const int* in_sizes, int n_in,
                              void* d_out, int out_size, void* d_ws, size_t ws_size,
                              hipStream_t stream) {
    const float* x  = (const float*)d_in[0];   // [1,2048,1024]
    const float* gw = (const float*)d_in[1];   // [16,1024]
    const float* gp = (const float*)d_in[2];   // [16,768,1024]
    const float* up = (const float*)d_in[3];   // [16,768,1024]
    const float* dp = (const float*)d_in[4];   // [16,1024,768]
    float* out = (float*)d_out;

    char* ws = (char*)d_ws;
    int*   cnt     = (int*)ws;                       // 16 ints
    int*   nitems  = (int*)(ws + 64);
    int2*  items   = (int2*)(ws + 128);              // <=80 items
    int*   entries = (int*)(ws + 2048);              // E*T ints   (128 KB)
    float* wlist   = (float*)(ws + 2048 + 131072);   // E*T floats (128 KB)
    short* xb      = (short*)(ws + 2048 + 262144);   // T*H bf16   (4 MB)
    short* hmid    = xb + (size_t)T * H;             // 2T*I bf16  (6 MB)
    short* gpb     = hmid + (size_t)2 * T * I;       // E*I*H bf16 (24 MB)
    short* upb     = gpb + (size_t)E * I * H;
    short* dpb     = upb + (size_t)E * I * H;
    const size_t NEED = 2048 + 262144 + (size_t)T * H * 2 + (size_t)2 * T * I * 2
                      + 3 * (size_t)E * I * H * 2;   // ~86.3 MB
    const bool big = ws_size >= NEED;                // launch-constant: graph-safe

    hipMemsetAsync(ws, 0, 2048, stream);
    hipMemsetAsync(out, 0, (size_t)T * H * sizeof(float), stream);

    cvt_kernel<<<T * H / 2048, 256, 0, stream>>>(x, xb);
    router_kernel<<<T / 4, 256, 0, stream>>>(x, gw, cnt, entries, wlist);
    build_worklist<<<1, 64, 0, stream>>>(cnt, items, nitems);

    if (big) {
        cvt_kernel<<<E * I * H / 2048, 256, 0, stream>>>(gp, gpb);
        cvt_kernel<<<E * I * H / 2048, 256, 0, stream>>>(up, upb);
        cvt_kernel<<<E * H * I / 2048, 256, 0, stream>>>(dp, dpb);
        gateup_mfma_dma<<<dim3(WMAX, I / 128), 256, 0, stream>>>(
            xb, gpb, upb, cnt, entries, nitems, items, hmid);
        down_mfma_dma<<<dim3(WMAX, H / 256), 256, 0, stream>>>(
            hmid, dpb, cnt, entries, wlist, nitems, items, out);
    } else {
        gateup_mfma_f32<<<dim3(WMAX, I / 128), 256, 0, stream>>>(
            xb, gp, up, cnt, entries, nitems, items, hmid);
        down_mfma_f32<<<dim3(WMAX, H / 256), 256, 0, stream>>>(
            hmid, dp, cnt, entries, wlist, nitems, items, out);
    }
}

// Round 4
// 307.443 us; speedup vs baseline: 4.2392x; 1.1289x over previous
//
#include <hip/hip_runtime.h>
#include <hip/hip_bf16.h>
#include <cmath>

// Problem constants (Qwen3 MoE block)
constexpr int T = 2048;   // tokens (B*S)
constexpr int H = 1024;   // hidden
constexpr int I = 768;    // intermediate
constexpr int E = 16;     // experts
constexpr int WMAX = 48;  // max worklist items at M=128 (sum ceil(n_e/128) <= 48)

typedef short short8 __attribute__((ext_vector_type(8)));
typedef float f32x4  __attribute__((ext_vector_type(4)));

__device__ __forceinline__ short f2bf(float f) {
    __hip_bfloat16 h = __float2bfloat16(f);   // RNE
    return *reinterpret_cast<short*>(&h);
}

__device__ __forceinline__ short8 pack8(float4 a, float4 b) {
    short8 v = {f2bf(a.x), f2bf(a.y), f2bf(a.z), f2bf(a.w),
                f2bf(b.x), f2bf(b.y), f2bf(b.z), f2bf(b.w)};
    return v;
}

// XOR-swizzled LDS index (units: shorts). Row stride 32 bf16 = 64 B.
// Proven conflict-free in round 2 (SQ_LDS_BANK_CONFLICT = 0).
__device__ __forceinline__ int sw(int r, int kg) {
    return r * 32 + (((kg + (r >> 1)) & 3) << 3);
}

// ------------------------------------------------------------------
// x fp32 -> bf16 (x re-read by 12 N-tiles in gateup; convert once)
// ------------------------------------------------------------------
__global__ __launch_bounds__(256) void cvt_x_kernel(
    const float* __restrict__ x, short* __restrict__ xb)
{
    size_t i = (size_t)blockIdx.x * 256 + threadIdx.x;   // one short8 per thread
    const float4* s4 = (const float4*)x;
    float4 a = s4[2 * i], b = s4[2 * i + 1];
    *(short8*)(xb + i * 8) = pack8(a, b);
}

// ------------------------------------------------------------------
// Router: block = 16 tokens x 16 experts, one fp32 dot per thread.
// Same-address loads broadcast within the wave; fp32-exact logits.
// ------------------------------------------------------------------
__global__ __launch_bounds__(256) void router_kernel(
    const float* __restrict__ x,     // [T,H]
    const float* __restrict__ gw,    // [E,H]
    int* __restrict__ cnt,           // [E]
    int* __restrict__ entries,       // [E,T]  value = t*2 + k
    float* __restrict__ wlist)       // [E,T]
{
    const int tid = threadIdx.x;
    const int tl = tid & 15, e = tid >> 4;
    const int t = blockIdx.x * 16 + tl;

    const float4* xr = (const float4*)(x + (size_t)t * H);
    const float4* gr = (const float4*)(gw + (size_t)e * H);
    float s0 = 0.f, s1 = 0.f;
    #pragma unroll 8
    for (int q = 0; q < 256; q += 2) {
        float4 a = xr[q],     b = gr[q];
        float4 c = xr[q + 1], d = gr[q + 1];
        s0 += a.x * b.x + a.y * b.y + a.z * b.z + a.w * b.w;
        s1 += c.x * d.x + c.y * d.y + c.z * d.z + c.w * d.w;
    }

    __shared__ float lg[16][17];
    lg[tl][e] = s0 + s1;
    __syncthreads();

    if (tid < 16) {
        int tk = blockIdx.x * 16 + tid;
        float v1 = -3.0e38f, v2 = -3.0e38f;
        int i1 = 0, i2 = 0;
        #pragma unroll
        for (int k = 0; k < E; ++k) {
            float v = lg[tid][k];
            if (v > v1) { v2 = v1; i2 = i1; v1 = v; i1 = k; }
            else if (v > v2) { v2 = v; i2 = k; }
        }
        // renormalized top-2 softmax == softmax over the two winning logits
        float w1 = 1.f / (1.f + expf(v2 - v1));
        float w2 = 1.f - w1;
        int p = atomicAdd(&cnt[i1], 1);
        entries[i1 * T + p] = tk * 2;
        wlist[i1 * T + p] = w1;
        p = atomicAdd(&cnt[i2], 1);
        entries[i2 * T + p] = tk * 2 + 1;
        wlist[i2 * T + p] = w2;
    }
}

// ------------------------------------------------------------------
// Work-list builder: flat (expert, t0) items, M-tile = 128.
// ------------------------------------------------------------------
__global__ void build_worklist(const int* __restrict__ cnt,
                               int2* __restrict__ items,
                               int* __restrict__ nitems)
{
    if (threadIdx.x == 0) {
        int c = 0;
        for (int e = 0; e < E; ++e) {
            int n = cnt[e];
            for (int t0 = 0; t0 < n; t0 += 128) items[c++] = make_int2(e, t0);
        }
        *nitems = c;
    }
}

// ------------------------------------------------------------------
// Grouped gate/up GEMM + SwiGLU, bf16 MFMA, fp32 weights converted
// in-register during staging. Tile M=128 x N=64, BK=32.
// Register prefetch: next K-chunk's global loads issue before the
// barrier, in flight during MFMA of the current chunk.
// ------------------------------------------------------------------
__global__ __launch_bounds__(256) void gateup_mfma(
    const short* __restrict__ xb,      // [T,H] bf16
    const float* __restrict__ gate_p,  // [E,I,H] f32
    const float* __restrict__ up_p,    // [E,I,H] f32
    const int* __restrict__ cnt,
    const int* __restrict__ entries,
    const int* __restrict__ nitems,
    const int2* __restrict__ items,
    short* __restrict__ hmid)          // [2T,I] bf16, row = slot = t*2+k
{
    if (blockIdx.x >= *nitems) return;
    const int e  = items[blockIdx.x].x;
    const int t0 = items[blockIdx.x].y;
    const int n  = cnt[e];
    const int i0 = blockIdx.y * 64;

    __shared__ short Xs[128 * 32];
    __shared__ short Gs[64 * 32];
    __shared__ short Us[64 * 32];
    __shared__ int toks[128];

    const int tid = threadIdx.x;
    if (tid < 128) {
        int r = t0 + tid;
        toks[tid] = (r < n) ? entries[e * T + r] : -1;
    }
    __syncthreads();

    const int lane = tid & 63, wave = tid >> 6;
    const int m16 = lane & 15, q = lane >> 4;

    // staging coords: 64-row groups, 4 threads/row covering the 4 k-slots
    const int sr = tid >> 2, skg = tid & 3;
    const int xt0 = toks[sr], xt1 = toks[64 + sr];
    const short* xsrc0 = xb + (size_t)((xt0 >= 0 ? xt0 : 0) >> 1) * H + skg * 8;
    const short* xsrc1 = xb + (size_t)((xt1 >= 0 ? xt1 : 0) >> 1) * H + skg * 8;
    const float* gsrc = gate_p + (size_t)e * I * H + (size_t)(i0 + sr) * H + skg * 8;
    const float* usrc = up_p   + (size_t)e * I * H + (size_t)(i0 + sr) * H + skg * 8;

    f32x4 accg[8], accu[8];
    #pragma unroll
    for (int a = 0; a < 8; ++a) {
        accg[a] = (f32x4){0.f, 0.f, 0.f, 0.f};
        accu[a] = (f32x4){0.f, 0.f, 0.f, 0.f};
    }

    // prologue loads (k0 = 0)
    short8 xc0 = *(const short8*)xsrc0;
    short8 xc1 = *(const short8*)xsrc1;
    float4 gc0 = *(const float4*)gsrc, gc1 = *(const float4*)(gsrc + 4);
    float4 uc0 = *(const float4*)usrc, uc1 = *(const float4*)(usrc + 4);

    for (int k0 = 0; k0 < H; k0 += 32) {
        // store current chunk to LDS (convert f32->bf16 for weights)
        *(short8*)&Xs[sw(sr, skg)]      = xc0;
        *(short8*)&Xs[sw(64 + sr, skg)] = xc1;
        *(short8*)&Gs[sw(sr, skg)] = pack8(gc0, gc1);
        *(short8*)&Us[sw(sr, skg)] = pack8(uc0, uc1);
        // prefetch next chunk (in flight during MFMA below)
        int kn = (k0 + 32 < H) ? k0 + 32 : 0;
        xc0 = *(const short8*)(xsrc0 + kn);
        xc1 = *(const short8*)(xsrc1 + kn);
        gc0 = *(const float4*)(gsrc + kn); gc1 = *(const float4*)(gsrc + kn + 4);
        uc0 = *(const float4*)(usrc + kn); uc1 = *(const float4*)(usrc + kn + 4);
        __syncthreads();

        short8 bg = *(const short8*)&Gs[sw(wave * 16 + m16, q)];
        short8 bu = *(const short8*)&Us[sw(wave * 16 + m16, q)];
        #pragma unroll
        for (int mi = 0; mi < 8; ++mi) {
            short8 af = *(const short8*)&Xs[sw(mi * 16 + m16, q)];
            accg[mi] = __builtin_amdgcn_mfma_f32_16x16x32_bf16(af, bg, accg[mi], 0, 0, 0);
            accu[mi] = __builtin_amdgcn_mfma_f32_16x16x32_bf16(af, bu, accu[mi], 0, 0, 0);
        }
        __syncthreads();
    }

    // epilogue: SwiGLU, scalar bf16 stores
    const int col = i0 + wave * 16 + m16;
    #pragma unroll
    for (int mi = 0; mi < 8; ++mi)
        #pragma unroll
        for (int j = 0; j < 4; ++j) {
            int row = mi * 16 + q * 4 + j;
            int slot = toks[row];
            if (slot < 0) continue;
            float g = accg[mi][j];
            float u = accu[mi][j];
            float hv = g / (1.f + expf(-g)) * u;
            ((unsigned short*)hmid)[(size_t)slot * I + col] = (unsigned short)f2bf(hv);
        }
}

// ------------------------------------------------------------------
// Grouped down GEMM, bf16 MFMA, fp32 weights converted in staging.
// Tile M=128 x N=128, BK=32, register prefetch. f32 atomic combine.
// ------------------------------------------------------------------
__global__ __launch_bounds__(256) void down_mfma(
    const short* __restrict__ hmid,    // [2T,I] bf16
    const float* __restrict__ down_p,  // [E,H,I] f32
    const int* __restrict__ cnt,
    const int* __restrict__ entries,
    const float* __restrict__ wlist,
    const int* __restrict__ nitems,
    const int2* __restrict__ items,
    float* __restrict__ out)           // [T,H], pre-zeroed
{
    if (blockIdx.x >= *nitems) return;
    const int e  = items[blockIdx.x].x;
    const int t0 = items[blockIdx.x].y;
    const int n  = cnt[e];
    const int h0 = blockIdx.y * 128;

    __shared__ short As[128 * 32];
    __shared__ short Bs[128 * 32];
    __shared__ int toks[128];
    __shared__ float wr[128];

    const int tid = threadIdx.x;
    if (tid < 128) {
        int r = t0 + tid;
        bool v = (r < n);
        toks[tid] = v ? entries[e * T + r] : -1;
        wr[tid]   = v ? wlist[e * T + r] : 0.f;
    }
    __syncthreads();

    const int lane = tid & 63, wave = tid >> 6;
    const int m16 = lane & 15, q = lane >> 4;

    const int sr = tid >> 2, skg = tid & 3;
    const int at0 = toks[sr], at1 = toks[64 + sr];
    const short* asrc0 = hmid + (size_t)(at0 >= 0 ? at0 : 0) * I + skg * 8;
    const short* asrc1 = hmid + (size_t)(at1 >= 0 ? at1 : 0) * I + skg * 8;
    const float* bsrc0 = down_p + (size_t)e * H * I + (size_t)(h0 + sr) * I + skg * 8;
    const float* bsrc1 = down_p + (size_t)e * H * I + (size_t)(h0 + 64 + sr) * I + skg * 8;

    f32x4 acc[8][2];
    #pragma unroll
    for (int a = 0; a < 8; ++a)
        #pragma unroll
        for (int b = 0; b < 2; ++b)
            acc[a][b] = (f32x4){0.f, 0.f, 0.f, 0.f};

    short8 ac0 = *(const short8*)asrc0;
    short8 ac1 = *(const short8*)asrc1;
    float4 bc0 = *(const float4*)bsrc0, bc1 = *(const float4*)(bsrc0 + 4);
    float4 bc2 = *(const float4*)bsrc1, bc3 = *(const float4*)(bsrc1 + 4);

    for (int k0 = 0; k0 < I; k0 += 32) {
        *(short8*)&As[sw(sr, skg)]      = ac0;
        *(short8*)&As[sw(64 + sr, skg)] = ac1;
        *(short8*)&Bs[sw(sr, skg)]      = pack8(bc0, bc1);
        *(short8*)&Bs[sw(64 + sr, skg)] = pack8(bc2, bc3);
        int kn = (k0 + 32 < I) ? k0 + 32 : 0;
        ac0 = *(const short8*)(asrc0 + kn);
        ac1 = *(const short8*)(asrc1 + kn);
        bc0 = *(const float4*)(bsrc0 + kn); bc1 = *(const float4*)(bsrc0 + kn + 4);
        bc2 = *(const float4*)(bsrc1 + kn); bc3 = *(const float4*)(bsrc1 + kn + 4);
        __syncthreads();

        short8 bf0 = *(const short8*)&Bs[sw(wave * 32 + m16, q)];
        short8 bf1 = *(const short8*)&Bs[sw(wave * 32 + 16 + m16, q)];
        #pragma unroll
        for (int mi = 0; mi < 8; ++mi) {
            short8 af = *(const short8*)&As[sw(mi * 16 + m16, q)];
            acc[mi][0] = __builtin_amdgcn_mfma_f32_16x16x32_bf16(af, bf0, acc[mi][0], 0, 0, 0);
            acc[mi][1] = __builtin_amdgcn_mfma_f32_16x16x32_bf16(af, bf1, acc[mi][1], 0, 0, 0);
        }
        __syncthreads();
    }

    #pragma unroll
    for (int mi = 0; mi < 8; ++mi)
        #pragma unroll
        for (int ni = 0; ni < 2; ++ni)
            #pragma unroll
            for (int j = 0; j < 4; ++j) {
                int row = mi * 16 + q * 4 + j;
                int slot = toks[row];
                if (slot < 0) continue;
                int t = slot >> 1;
                float w = wr[row];
                int col = h0 + wave * 32 + ni * 16 + m16;
                atomicAdd(&out[(size_t)t * H + col], w * acc[mi][ni][j]);
            }
}

extern "C" void kernel_launch(void* const* d_in, const int* in_sizes, int n_in,
                              void* d_out, int out_size, void* d_ws, size_t ws_size,
                              hipStream_t stream) {
    const float* x  = (const float*)d_in[0];   // [1,2048,1024]
    const float* gw = (const float*)d_in[1];   // [16,1024]
    const float* gp = (const float*)d_in[2];   // [16,768,1024]
    const float* up = (const float*)d_in[3];   // [16,768,1024]
    const float* dp = (const float*)d_in[4];   // [16,1024,768]
    float* out = (float*)d_out;

    char* ws = (char*)d_ws;
    int*   cnt     = (int*)ws;                       // 16 ints
    int*   nitems  = (int*)(ws + 64);
    int2*  items   = (int2*)(ws + 128);              // <=48 items
    int*   entries = (int*)(ws + 2048);              // E*T ints   (128 KB)
    float* wlist   = (float*)(ws + 2048 + 131072);   // E*T floats (128 KB)
    short* xb      = (short*)(ws + 2048 + 262144);   // T*H bf16   (4 MB)
    short* hmid    = xb + (size_t)T * H;             // 2T*I bf16  (6 MB)
    // total ~10.7 MB (round 1 proved ws >= 12.7 MB)

    hipMemsetAsync(ws, 0, 2048, stream);
    hipMemsetAsync(out, 0, (size_t)T * H * sizeof(float), stream);

    cvt_x_kernel<<<T * H / 2048, 256, 0, stream>>>(x, xb);
    router_kernel<<<T / 16, 256, 0, stream>>>(x, gw, cnt, entries, wlist);
    build_worklist<<<1, 64, 0, stream>>>(cnt, items, nitems);
    gateup_mfma<<<dim3(WMAX, I / 64), 256, 0, stream>>>(
        xb, gp, up, cnt, entries, nitems, items, hmid);
    down_mfma<<<dim3(WMAX, H / 128), 256, 0, stream>>>(
        hmid, dp, cnt, entries, wlist, nitems, items, out);
}